// Round 5
// baseline (84.445 us; speedup 1.0000x reference)
//
#include <hip/hip_runtime.h>
#include <math.h>

namespace {
constexpr int B = 32, C = 2, T = 262144, K = 6;
constexpr int SEG = 2048;         // segments per (b,c)
constexpr int L = T / SEG;        // 128 samples per segment
constexpr int NBC = B * C;        // 64 sequences
constexpr int NST = 2 * K;        // 12-dim cascade state
constexpr int LOG2L = 7;          // L = 2^7
constexpr int TS = 16;            // samples per staging tile
constexpr int NT = L / TS;        // 8 tiles
constexpr int WPB = SEG / 64;     // 32 one-wave blocks per (b,c)
constexpr int GP = 8;             // segments per scan thread
constexpr int NW = 4;             // scan waves per block (256 threads)
constexpr float FS = 44100.0f;
}

__device__ __forceinline__ float rl(float v, int lane) {
  return __int_as_float(__builtin_amdgcn_readlane(__float_as_int(v), lane));
}

__device__ __forceinline__ void ld12(const float* p, float (&v)[NST]) {
  const float4* q = reinterpret_cast<const float4*>(p);
  float4 a = q[0], b4 = q[1], c4 = q[2];
  v[0] = a.x; v[1] = a.y; v[2] = a.z; v[3] = a.w;
  v[4] = b4.x; v[5] = b4.y; v[6] = b4.z; v[7] = b4.w;
  v[8] = c4.x; v[9] = c4.y; v[10] = c4.z; v[11] = c4.w;
}

__device__ __forceinline__ void st12(float* p, const float (&v)[NST]) {
  float4* q = reinterpret_cast<float4*>(p);
  q[0] = make_float4(v[0], v[1], v[2], v[3]);
  q[1] = make_float4(v[4], v[5], v[6], v[7]);
  q[2] = make_float4(v[8], v[9], v[10], v[11]);
}

// s = M*s + z (12x12 affine step, fully register-resident)
__device__ __forceinline__ void affine(const float (&M)[NST][NST], float (&s)[NST],
                                       const float (&z)[NST]) {
  float ns[NST];
#pragma unroll
  for (int r = 0; r < NST; ++r) {
    float a = z[r];
#pragma unroll
    for (int m = 0; m < NST; ++m) a = fmaf(M[r][m], s[m], a);
    ns[r] = a;
  }
#pragma unroll
  for (int r = 0; r < NST; ++r) s[r] = ns[r];
}

// RBJ peaking-EQ coefficients for batch b (all K bands), normalized by a0.
__device__ __forceinline__ void coeffs_for_b(const float* __restrict__ fr,
                                             const float* __restrict__ gn,
                                             const float* __restrict__ qf, int b,
                                             float (&cb0)[K], float (&cb1)[K],
                                             float (&cb2)[K], float (&ca1)[K],
                                             float (&ca2)[K]) {
#pragma unroll
  for (int k = 0; k < K; ++k) {
    float f = fr[b * K + k], g = gn[b * K + k], Q = qf[b * K + k];
    float A  = powf(10.0f, g * (1.0f / 40.0f));
    float w0 = 6.283185307179586f * f / FS;
    float cw = cosf(w0);
    float al = sinf(w0) / (2.0f * Q);
    float ia = 1.0f / (1.0f + al / A);
    cb0[k] = (1.0f + al * A) * ia;
    cb1[k] = (-2.0f * cw) * ia;
    cb2[k] = (1.0f - al * A) * ia;
    ca1[k] = (-2.0f * cw) * ia;
    ca2[k] = (1.0f - al / A) * ia;
  }
}

// Segment pass, 1 wave per block, LDS transpose-staged I/O, depth-2 prefetch.
// WRITE_OUT=false: computes coeffs inline (stores cf once per b), zero-state
// run, records final 12-dim state. WRITE_OUT=true: loads cf, runs from exact
// incoming state, writes output.
template <bool WRITE_OUT>
__global__ __launch_bounds__(64, 2) void eq_pass(const float* __restrict__ x,
                                                 const float* __restrict__ fr,
                                                 const float* __restrict__ gn,
                                                 const float* __restrict__ qf,
                                                 float* __restrict__ cf,
                                                 const float* __restrict__ st_in,
                                                 float* __restrict__ st_out,
                                                 float* __restrict__ y) {
  __shared__ float sIn[2][64][17];
  __shared__ float sOut[2][64][17];

  int l = threadIdx.x;
  int wid = blockIdx.x;           // 0 .. NBC*WPB-1
  int bc = wid / WPB;
  int segbase = (wid % WPB) * 64;
  int b = bc / C;
  int tid = bc * SEG + segbase + l;

  const float4* xp4 = reinterpret_cast<const float4*>(x + (size_t)bc * T + (size_t)segbase * L);
  float4* yp4 = reinterpret_cast<float4*>(y + (size_t)bc * T + (size_t)segbase * L);
  constexpr int Q4 = L / 4;  // 32 float4 per segment

  int sj = l >> 2;   // staging sub-segment 0..15
  int qj = l & 3;    // 16B quarter of the 64B line

  // issue prologue loads FIRST (latency hides under coeff computation)
  float4 ra[4], rb[4];
#pragma unroll
  for (int j = 0; j < 4; ++j) ra[j] = xp4[(size_t)(j * 16 + sj) * Q4 + qj];
#pragma unroll
  for (int j = 0; j < 4; ++j) rb[j] = xp4[(size_t)(j * 16 + sj) * Q4 + 4 + qj];

  float b0[K], b1c[K], b2c[K], a1c[K], a2c[K];
  if (!WRITE_OUT) {
    coeffs_for_b(fr, gn, qf, b, b0, b1c, b2c, a1c, a2c);
    // one block per b publishes cf for eq_scan / eq_pass<true>
    if ((wid % (WPB * C)) == 0) {
#pragma unroll
      for (int k = 0; k < K; ++k) {
        if (l == k) {
          float* p = cf + (b * K + k) * 5;
          p[0] = b0[k]; p[1] = b1c[k]; p[2] = b2c[k]; p[3] = a1c[k]; p[4] = a2c[k];
        }
      }
    }
  } else {
#pragma unroll
    for (int k = 0; k < K; ++k) {
      const float* p = cf + (b * K + k) * 5;
      b0[k] = p[0]; b1c[k] = p[1]; b2c[k] = p[2]; a1c[k] = p[3]; a2c[k] = p[4];
    }
  }

  float s1[K], s2[K];
  if (WRITE_OUT) {
    float st[NST];
    ld12(st_in + (size_t)tid * NST, st);
#pragma unroll
    for (int k = 0; k < K; ++k) { s1[k] = st[2 * k]; s2[k] = st[2 * k + 1]; }
  } else {
#pragma unroll
    for (int k = 0; k < K; ++k) { s1[k] = 0.0f; s2[k] = 0.0f; }
  }

  auto tile = [&](float4 (&r)[4], int t, int pb) {
    // stage tile t (regs -> LDS, transposed)
#pragma unroll
    for (int j = 0; j < 4; ++j) {
      int seg = j * 16 + sj;
      sIn[pb][seg][qj * 4 + 0] = r[j].x;
      sIn[pb][seg][qj * 4 + 1] = r[j].y;
      sIn[pb][seg][qj * 4 + 2] = r[j].z;
      sIn[pb][seg][qj * 4 + 3] = r[j].w;
    }
    // issue loads for tile t+2
    if (t + 2 < NT) {
#pragma unroll
      for (int j = 0; j < 4; ++j)
        r[j] = xp4[(size_t)(j * 16 + sj) * Q4 + (size_t)(t + 2) * 4 + qj];
    }
    // own segment: 16 sequential samples through the 6-stage cascade
    float out16[TS];
#pragma unroll
    for (int i = 0; i < TS; ++i) {
      float yv = sIn[pb][l][i];
#pragma unroll
      for (int k = 0; k < K; ++k) {
        float yk = fmaf(b0[k], yv, s1[k]);
        float t1 = fmaf(b1c[k], yv, s2[k]);
        s1[k] = fmaf(-a1c[k], yk, t1);
        float t2 = b2c[k] * yv;
        s2[k] = fmaf(-a2c[k], yk, t2);
        yv = yk;
      }
      out16[i] = yv;
    }
    if (WRITE_OUT) {
#pragma unroll
      for (int i = 0; i < TS; ++i) sOut[pb][l][i] = out16[i];
      // flush as full 64B lines
#pragma unroll
      for (int j = 0; j < 4; ++j) {
        int seg = j * 16 + sj;
        float4 o;
        o.x = sOut[pb][seg][qj * 4 + 0];
        o.y = sOut[pb][seg][qj * 4 + 1];
        o.z = sOut[pb][seg][qj * 4 + 2];
        o.w = sOut[pb][seg][qj * 4 + 3];
        yp4[(size_t)seg * Q4 + (size_t)t * 4 + qj] = o;
      }
    }
  };

  for (int tt = 0; tt < NT; tt += 2) {
    tile(ra, tt, 0);
    tile(rb, tt + 1, 1);
  }

  if (!WRITE_OUT) {
    float st[NST];
#pragma unroll
    for (int k = 0; k < K; ++k) { st[2 * k] = s1[k]; st[2 * k + 1] = s2[k]; }
    st12(st_out + (size_t)tid * NST, st);
  }
}

// K3: hierarchical scan, 256 threads (4 waves) per (b,c).
// Thread t owns GP=8 segments. Phase A: squaring chain A -> Phi=A^L ->
// Phi_g=A^(GP*L) -> Phi_w=Phi_g^64 (lane-column form, wave-redundant).
// Phase B: per-thread zero-incoming group final (Phi replicated in VGPRs).
// C1a: 64-step wave serial scan (readlane) -> wave final. C2: <=3-step block
// scan with Phi_w -> wave incoming. C1b: re-scan from true incoming, store
// per-group incoming. Phase D: per-thread replay emits per-segment states.
__global__ __launch_bounds__(256, 1) void eq_scan(const float* __restrict__ cf,
                                                  const float* __restrict__ zsf,
                                                  float* __restrict__ sif) {
  __shared__ float PhiL[NST][NST];        // Phi rows
  __shared__ float Rg[NST][NST + 1];      // Phi_g columns (transpose scratch)
  __shared__ float Rw[NST][NST + 1];      // Phi_w columns
  __shared__ float FB[NW][64][NST + 1];   // per-group zero-incoming finals
  __shared__ float SL[NW][64][NST + 1];   // per-group true incoming states
  __shared__ float WF[NW][NST + 1];       // wave finals

  int bc = blockIdx.x;
  int b = bc / C;
  int t = threadIdx.x;
  int w = t >> 6;
  int l = t & 63;
  bool act = (l < NST);

  float b0[K], b1c[K], b2c[K], a1c[K], a2c[K];
#pragma unroll
  for (int k = 0; k < K; ++k) {
    const float* p = cf + (b * K + k) * 5;
    b0[k] = p[0]; b1c[k] = p[1]; b2c[k] = p[2]; a1c[k] = p[3]; a2c[k] = p[4];
  }

  // column l of the one-sample homogeneous map A
  float col[NST];
  {
    float s1[K], s2[K];
#pragma unroll
    for (int k = 0; k < K; ++k) {
      s1[k] = (l == 2 * k) ? 1.0f : 0.0f;
      s2[k] = (l == 2 * k + 1) ? 1.0f : 0.0f;
    }
    float yv = 0.0f;
#pragma unroll
    for (int k = 0; k < K; ++k) {
      float yk = fmaf(b0[k], yv, s1[k]);
      float t1 = fmaf(b1c[k], yv, s2[k]);
      float ns1 = fmaf(-a1c[k], yk, t1);
      float ns2 = fmaf(-a2c[k], yk, b2c[k] * yv);
      s1[k] = ns1; s2[k] = ns2; yv = yk;
    }
#pragma unroll
    for (int k = 0; k < K; ++k) { col[2 * k] = s1[k]; col[2 * k + 1] = s2[k]; }
  }

  auto square = [&]() {
    float nc[NST];
#pragma unroll
    for (int r = 0; r < NST; ++r) nc[r] = 0.0f;
#pragma unroll
    for (int m = 0; m < NST; ++m) {
      float wv = col[m];
#pragma unroll
      for (int r = 0; r < NST; ++r) nc[r] = fmaf(rl(col[r], m), wv, nc[r]);
    }
#pragma unroll
    for (int r = 0; r < NST; ++r) col[r] = nc[r];
  };

  for (int p = 0; p < LOG2L; ++p) square();          // Phi = A^L
  if (w == 0 && act) {
#pragma unroll
    for (int r = 0; r < NST; ++r) PhiL[r][l] = col[r];
  }
  for (int p = 0; p < 3; ++p) square();              // Phi_g = A^(GP*L)
  if (w == 0 && act) {
#pragma unroll
    for (int r = 0; r < NST; ++r) Rg[r][l] = col[r];
  }
  for (int p = 0; p < 6; ++p) square();              // Phi_w = Phi_g^64
  if (w == 0 && act) {
#pragma unroll
    for (int r = 0; r < NST; ++r) Rw[r][l] = col[r];
  }
  __syncthreads();

  float rowg[NST], roww[NST];
#pragma unroll
  for (int m = 0; m < NST; ++m) {
    rowg[m] = act ? Rg[l][m] : 0.0f;
    roww[m] = act ? Rw[l][m] : 0.0f;
  }
  float phi[NST][NST];
#pragma unroll
  for (int r = 0; r < NST; ++r)
#pragma unroll
    for (int m = 0; m < NST; ++m) phi[r][m] = PhiL[r][m];

  // Phase B: zero-incoming final over this thread's GP segments
  const float* zb = zsf + ((size_t)bc * SEG + (size_t)t * GP) * NST;
  float s[NST];
  ld12(zb, s);  // after segment 0: s = Phi*0 + z0
#pragma unroll
  for (int j = 1; j < GP; ++j) {
    float zc[NST];
    ld12(zb + (size_t)j * NST, zc);
    affine(phi, s, zc);
  }
#pragma unroll
  for (int r = 0; r < NST; ++r) FB[w][l][r] = s[r];
  __syncthreads();

  // C1a: wave serial scan (zero incoming) -> wave final
  {
    float sv = 0.0f;
    for (int i = 0; i < 64; ++i) {
      float wv = act ? FB[w][i][l] : 0.0f;
      float t0 = fmaf(rowg[0], rl(sv, 0), fmaf(rowg[1], rl(sv, 1), rowg[2] * rl(sv, 2)));
      float t1 = fmaf(rowg[3], rl(sv, 3), fmaf(rowg[4], rl(sv, 4), rowg[5] * rl(sv, 5)));
      float t2 = fmaf(rowg[6], rl(sv, 6), fmaf(rowg[7], rl(sv, 7), rowg[8] * rl(sv, 8)));
      float t3 = fmaf(rowg[9], rl(sv, 9), fmaf(rowg[10], rl(sv, 10), rowg[11] * rl(sv, 11)));
      sv = ((t0 + t1) + (t2 + t3)) + wv;
    }
    if (act) WF[w][l] = sv;
  }
  __syncthreads();

  // C2: block scan over wave finals (wave w does w steps; wave 0 none)
  float swv = 0.0f;
  for (int w2 = 0; w2 < w; ++w2) {
    float wfv = act ? WF[w2][l] : 0.0f;
    float t0 = fmaf(roww[0], rl(swv, 0), fmaf(roww[1], rl(swv, 1), roww[2] * rl(swv, 2)));
    float t1 = fmaf(roww[3], rl(swv, 3), fmaf(roww[4], rl(swv, 4), roww[5] * rl(swv, 5)));
    float t2 = fmaf(roww[6], rl(swv, 6), fmaf(roww[7], rl(swv, 7), roww[8] * rl(swv, 8)));
    float t3 = fmaf(roww[9], rl(swv, 9), fmaf(roww[10], rl(swv, 10), roww[11] * rl(swv, 11)));
    swv = ((t0 + t1) + (t2 + t3)) + wfv;
  }

  // C1b: re-scan from true wave incoming; store per-group incoming states
  {
    float sv = swv;
    for (int i = 0; i < 64; ++i) {
      if (act) SL[w][i][l] = sv;
      float wv = act ? FB[w][i][l] : 0.0f;
      float t0 = fmaf(rowg[0], rl(sv, 0), fmaf(rowg[1], rl(sv, 1), rowg[2] * rl(sv, 2)));
      float t1 = fmaf(rowg[3], rl(sv, 3), fmaf(rowg[4], rl(sv, 4), rowg[5] * rl(sv, 5)));
      float t2 = fmaf(rowg[6], rl(sv, 6), fmaf(rowg[7], rl(sv, 7), rowg[8] * rl(sv, 8)));
      float t3 = fmaf(rowg[9], rl(sv, 9), fmaf(rowg[10], rl(sv, 10), rowg[11] * rl(sv, 11)));
      sv = ((t0 + t1) + (t2 + t3)) + wv;
    }
  }
  __syncthreads();

  // Phase D: replay — emit incoming state of each owned segment
  float sg[NST];
#pragma unroll
  for (int r = 0; r < NST; ++r) sg[r] = SL[w][l][r];
  float* ob = sif + ((size_t)bc * SEG + (size_t)t * GP) * NST;
#pragma unroll
  for (int j = 0; j < GP; ++j) {
    st12(ob + (size_t)j * NST, sg);
    if (j + 1 < GP) {
      float zc[NST];
      ld12(zb + (size_t)j * NST, zc);
      affine(phi, sg, zc);
    }
  }
}

extern "C" void kernel_launch(void* const* d_in, const int* in_sizes, int n_in,
                              void* d_out, int out_size, void* d_ws, size_t ws_size,
                              hipStream_t stream) {
  const float* audio = (const float*)d_in[0];
  const float* fr    = (const float*)d_in[1];
  const float* gn    = (const float*)d_in[2];
  const float* qf    = (const float*)d_in[3];
  float* out = (float*)d_out;

  // ws layout (floats): coeffs | zero-state finals | incoming states
  float* cf  = (float*)d_ws;                    // B*K*5 = 960
  float* zsf = cf + B * K * 5;                  // NBC*SEG*NST = 1572864
  float* sif = zsf + (size_t)NBC * SEG * NST;   // 1572864

  hipLaunchKernelGGL((eq_pass<false>), dim3(NBC * WPB), dim3(64), 0, stream,
                     audio, fr, gn, qf, cf, nullptr, zsf, out);
  hipLaunchKernelGGL(eq_scan, dim3(NBC), dim3(256), 0, stream, cf, zsf, sif);
  hipLaunchKernelGGL((eq_pass<true>), dim3(NBC * WPB), dim3(64), 0, stream,
                     audio, fr, gn, qf, cf, sif, nullptr, out);
}